// Round 9
// baseline (265.518 us; speedup 1.0000x reference)
//
#include <hip/hip_runtime.h>
#include <math.h>

#define B_DIM 8
#define N_DIM 2048
#define F_IN 256
#define F_OUT 128
#define ALPHA 0.2f
#define KPAD 136
#define NSPLIT 4
#define TPB 4            // tiles (of 128 n) per block in attn
#define PS ((size_t)B_DIM * N_DIM * F_OUT)  // partial-acc ns stride

typedef __attribute__((ext_vector_type(8))) short short8;
typedef __attribute__((ext_vector_type(4))) float floatx4;

static __device__ __forceinline__ unsigned short f2bf(float f) {
    unsigned u = __float_as_uint(f);
    u += 0x7fff + ((u >> 16) & 1);   // RNE
    return (unsigned short)(u >> 16);
}
static __device__ __forceinline__ unsigned fmap(float f) {
    int b = __float_as_int(f);
    return (unsigned)(b ^ ((b >> 31) | 0x80000000));
}
static __device__ __forceinline__ float funmap(unsigned u) {
    return __uint_as_float((u & 0x80000000u) ? (int)(u ^ 0x80000000u) : ~(int)u);
}

// ---------------- Kernel 1: WhT(bf16) produced DIRECTLY via operand-swapped MFMA ----------------
// D = Wt(A-op: f rows) x X(B-op: n cols) -> D[f][n]. Store: lanes contiguous in n
// (16 x 2B = 32B segments) instead of the R6-R8 stride-4096 scatter.
__global__ __launch_bounds__(256) void gemm_xw(const float* __restrict__ X,
                                               const float* __restrict__ W,
                                               const float* __restrict__ avec,
                                               unsigned short* __restrict__ WhT,
                                               float* __restrict__ s1,
                                               float* __restrict__ s2,
                                               unsigned* __restrict__ s2max_u) {
    __shared__ unsigned short Wt[F_OUT][KPAD];  // Wt[f][k] = bf16 W[k][f], 34 KB
    const int t = threadIdx.x;
    const int lane = t & 63, wave = t >> 6;
    const int m = lane & 15, q = lane >> 4;
    const int row0 = blockIdx.x * 64 + wave * 16;  // node-range base for this wave

    floatx4 acc[8];  // acc[ft]: D[f=ft*16+q*4+r][n=m]
#pragma unroll
    for (int ft = 0; ft < 8; ft++) acc[ft] = (floatx4){0.f, 0.f, 0.f, 0.f};

    const int n0 = (t & 31) * 4;
    const int kb = t >> 5;

    for (int half = 0; half < 2; half++) {
        // stage Wt[f][k] for this k-half
        const float* Wp = W + (size_t)(half * 128 + kb) * F_OUT + n0;
#pragma unroll
        for (int i = 0; i < 16; i++) {
            float4 w = *(const float4*)(Wp + (size_t)i * 8 * F_OUT);
            int kk = kb + i * 8;
            Wt[n0 + 0][kk] = f2bf(w.x);
            Wt[n0 + 1][kk] = f2bf(w.y);
            Wt[n0 + 2][kk] = f2bf(w.z);
            Wt[n0 + 3][kk] = f2bf(w.w);
        }
        __syncthreads();

        // X fragments: B-operand, lane&15 = node, k = q*8+j
        const float* xrow = X + (size_t)(row0 + m) * F_IN + half * 128 + q * 8;
        float4 xr[8];
#pragma unroll
        for (int kt = 0; kt < 4; kt++) {
            xr[2 * kt] = *(const float4*)(xrow + kt * 32);
            xr[2 * kt + 1] = *(const float4*)(xrow + kt * 32 + 4);
        }
#pragma unroll
        for (int kt = 0; kt < 4; kt++) {
            union { unsigned short u[8]; short8 v; } xf;
            float tmp[8] = {xr[2 * kt].x, xr[2 * kt].y, xr[2 * kt].z, xr[2 * kt].w,
                            xr[2 * kt + 1].x, xr[2 * kt + 1].y, xr[2 * kt + 1].z, xr[2 * kt + 1].w};
#pragma unroll
            for (int j = 0; j < 8; j++) xf.u[j] = f2bf(tmp[j]);
#pragma unroll
            for (int ft = 0; ft < 8; ft++) {
                short8 wv = *(const short8*)&Wt[ft * 16 + m][kt * 32 + q * 8];  // A-op: f=lane&15
                acc[ft] = __builtin_amdgcn_mfma_f32_16x16x32_bf16(wv, xf.v, acc[ft], 0, 0, 0);
            }
        }
        __syncthreads();
    }

    // ---- store WhT[f][n]: per (ft,r) lanes m are contiguous in n ----
    const int b = row0 >> 11;
    const int nloc = (row0 & 2047) + m;
    unsigned short* WTb = WhT + (size_t)b * F_OUT * N_DIM;
#pragma unroll
    for (int ft = 0; ft < 8; ft++) {
#pragma unroll
        for (int r = 0; r < 4; r++) {
            int f = ft * 16 + q * 4 + r;
            WTb[(size_t)f * N_DIM + nloc] = f2bf(acc[ft][r]);
        }
    }

    // ---- fused s1/s2: per lane, node = row0+m, f covered = {ft*16+q*4+r} ----
    float v1 = 0.f, v2 = 0.f;
#pragma unroll
    for (int ft = 0; ft < 8; ft++) {
        float4 a1q = *(const float4*)&avec[ft * 16 + q * 4];
        float4 a2q = *(const float4*)&avec[F_OUT + ft * 16 + q * 4];
        v1 = fmaf(acc[ft][0], a1q.x, v1); v1 = fmaf(acc[ft][1], a1q.y, v1);
        v1 = fmaf(acc[ft][2], a1q.z, v1); v1 = fmaf(acc[ft][3], a1q.w, v1);
        v2 = fmaf(acc[ft][0], a2q.x, v2); v2 = fmaf(acc[ft][1], a2q.y, v2);
        v2 = fmaf(acc[ft][2], a2q.z, v2); v2 = fmaf(acc[ft][3], a2q.w, v2);
    }
    v1 += __shfl_xor(v1, 16, 64); v1 += __shfl_xor(v1, 32, 64);
    v2 += __shfl_xor(v2, 16, 64); v2 += __shfl_xor(v2, 32, 64);
    if (lane < 16) {
        s1[row0 + m] = v1;
        s2[row0 + m] = v2;
    }
    float wmax = v2;  // q-copies identical -> wave max == max over the 16 nodes
#pragma unroll
    for (int mk = 8; mk >= 1; mk >>= 1) wmax = fmaxf(wmax, __shfl_xor(wmax, mk, 64));
    if (lane == 0) atomicMax(&s2max_u[b], fmap(wmax));
}

// ---------------- Kernel 2: masked-dense MFMA, n-split, register-diet ----------------
// Grid 1024 = 256 row-groups x 4 n-splits. Block: 4 waves / 64 rows / 4 tiles of 128 n.
// s2 from LDS slice; sreg committed to LDS before P-build; lsum in fp32.
__global__ __launch_bounds__(256, 2) void attn_mm(const float* __restrict__ A,
                                                  const unsigned short* __restrict__ WhT,
                                                  const float* __restrict__ s1,
                                                  const float* __restrict__ s2,
                                                  const unsigned* __restrict__ s2max_u,
                                                  float* __restrict__ pacc,
                                                  float* __restrict__ plsum) {
    __shared__ unsigned short Bs[2048 * 8];  // 32 KB, fragment-major granules
    __shared__ float s2l[512];               // 2 KB: this block's n-slice of s2

    const int t = threadIdx.x;
    const int lane = t & 63, wave = t >> 6;
    const int m = lane & 15, q = lane >> 4;
    const int ns = blockIdx.x >> 8;
    const int rg = blockIdx.x & 255;
    const int row0 = rg * 64;
    const int b = row0 >> 11;
    const int nbase = ns * 512;

    const unsigned short* WTb = WhT + (size_t)b * F_OUT * N_DIM;
    if (t < 128) *(float4*)&s2l[t * 4] = ((const float4*)(s2 + (size_t)b * N_DIM + nbase))[t];

    const int myrow = row0 + wave * 16 + m;
    const float s1m = s1[myrow];
    const float s2mx = funmap(s2max_u[b]);
    const float xs = s1m + s2mx;
    const float shift = fmaxf(xs, ALPHA * xs);
    const float* Arow = A + (size_t)myrow * N_DIM + nbase;

    const int iw0 = t >> 6;

    floatx4 acc[8];
#pragma unroll
    for (int nt = 0; nt < 8; nt++) acc[nt] = (floatx4){0.f, 0.f, 0.f, 0.f};
    float lsum = 0.f;

    __syncthreads();  // s2l ready

    for (int tl = 0; tl < TPB; tl++) {
        const int noff = tl * 128;

        // ---- B-tile loads (oldest in vmcnt order) ----
        uint4 sreg[8];
#pragma unroll
        for (int i = 0; i < 8; i++) {
            int iw = i * 4 + iw0;
            int cs = iw & 3, nts = iw >> 2;
            sreg[i] = *(const uint4*)(WTb + (size_t)(nts * 16 + m) * N_DIM + nbase + noff + cs * 32 + q * 8);
        }
        // ---- A loads (younger; P-build waits only these + sreg drain) ----
        float4 areg[8];
#pragma unroll
        for (int c = 0; c < 4; c++) {
            areg[2 * c] = *(const float4*)(Arow + noff + c * 32 + q * 8);
            areg[2 * c + 1] = *(const float4*)(Arow + noff + c * 32 + q * 8 + 4);
        }
        // ---- commit B tile to LDS immediately (sreg dies here) ----
#pragma unroll
        for (int i = 0; i < 8; i++)
            *(uint4*)&Bs[(size_t)(i * 256 + t) * 8] = sreg[i];

        // ---- P fragments (s2 from LDS) ----
        short8 pf[4];
#pragma unroll
        for (int c = 0; c < 4; c++) {
            float4 za = *(const float4*)&s2l[noff + c * 32 + q * 8];
            float4 zb = *(const float4*)&s2l[noff + c * 32 + q * 8 + 4];
            float aa[8] = {areg[2 * c].x, areg[2 * c].y, areg[2 * c].z, areg[2 * c].w,
                           areg[2 * c + 1].x, areg[2 * c + 1].y, areg[2 * c + 1].z, areg[2 * c + 1].w};
            float zz[8] = {za.x, za.y, za.z, za.w, zb.x, zb.y, zb.z, zb.w};
            union { unsigned short u[8]; short8 v; } pu;
#pragma unroll
            for (int j = 0; j < 8; j++) {
                float x = s1m + zz[j];
                float e = fmaxf(x, ALPHA * x);
                float p = aa[j] * __expf(e - shift);   // A in {0,1} -> exact mask
                pu.u[j] = f2bf(p);
                lsum += p;                              // fp32 sum (bf16 RNE unbiased)
            }
            pf[c] = pu.v;
        }
        __syncthreads();

        // ---- MFMA: stride-1 b128 fragment reads, conflict-free ----
#pragma unroll
        for (int c = 0; c < 4; c++)
#pragma unroll
            for (int nt = 0; nt < 8; nt++) {
                short8 bv = *(const short8*)&Bs[(size_t)((nt * 4 + c) * 64 + lane) * 8];
                acc[nt] = __builtin_amdgcn_mfma_f32_16x16x32_bf16(pf[c], bv, acc[nt], 0, 0, 0);
            }
        __syncthreads();
    }

    // ---- partial outputs ----
    lsum += __shfl_xor(lsum, 16, 64);
    lsum += __shfl_xor(lsum, 32, 64);
    if (q == 0) plsum[(size_t)ns * (B_DIM * N_DIM) + row0 + wave * 16 + m] = lsum;

    float* pa = pacc + (size_t)ns * PS;
#pragma unroll
    for (int r = 0; r < 4; r++) {
        float* prow = pa + (size_t)(row0 + wave * 16 + q * 4 + r) * F_OUT + m;
#pragma unroll
        for (int nt = 0; nt < 8; nt++) prow[nt * 16] = acc[nt][r];
    }
}

// ---------------- Kernel 3: epilogue — sum 4 partials, normalize ----------------
__global__ __launch_bounds__(256) void epi(const float* __restrict__ pacc,
                                           const float* __restrict__ plsum,
                                           float* __restrict__ out) {
    const int t = threadIdx.x;
    const int row = blockIdx.x * 8 + (t >> 5);
    const int c0 = (t & 31) * 4;
    float l = 0.f;
#pragma unroll
    for (int ns = 0; ns < NSPLIT; ns++) l += plsum[(size_t)ns * (B_DIM * N_DIM) + row];
    float4 v = make_float4(0.f, 0.f, 0.f, 0.f);
#pragma unroll
    for (int ns = 0; ns < NSPLIT; ns++) {
        float4 p = *(const float4*)(pacc + (size_t)ns * PS + (size_t)row * F_OUT + c0);
        v.x += p.x; v.y += p.y; v.z += p.z; v.w += p.w;
    }
    const float inv = 1.f / l;
    v.x *= inv; v.y *= inv; v.z *= inv; v.w *= inv;
    *(float4*)(out + (size_t)row * F_OUT + c0) = v;
}

extern "C" void kernel_launch(void* const* d_in, const int* in_sizes, int n_in,
                              void* d_out, int out_size, void* d_ws, size_t ws_size,
                              hipStream_t stream) {
    const float* X = (const float*)d_in[0];
    const float* A = (const float*)d_in[1];
    const float* W = (const float*)d_in[2];
    const float* avec = (const float*)d_in[3];
    float* out = (float*)d_out;

    char* ws = (char*)d_ws;
    unsigned short* WhT = (unsigned short*)ws;            ws += PS * 2;            // 4 MB
    float* s1 = (float*)ws;                               ws += B_DIM * N_DIM * 4;
    float* s2 = (float*)ws;                               ws += B_DIM * N_DIM * 4;
    unsigned* s2max_u = (unsigned*)ws;                    ws += 256;
    float* pacc = (float*)ws;                             ws += PS * NSPLIT * 4;   // 32 MB
    float* plsum = (float*)ws;                            // 4 x 64 KB

    hipMemsetAsync(s2max_u, 0, B_DIM * sizeof(unsigned), stream);  // 0 < fmap(any real)
    gemm_xw<<<B_DIM * N_DIM / 64, 256, 0, stream>>>(X, W, avec, WhT, s1, s2, s2max_u);
    attn_mm<<<256 * NSPLIT, 256, 0, stream>>>(A, WhT, s1, s2, s2max_u, pacc, plsum);
    epi<<<B_DIM * N_DIM / 8, 256, 0, stream>>>(pacc, plsum, out);
}